// Round 11
// baseline (187.329 us; speedup 1.0000x reference)
//
#include <hip/hip_runtime.h>
#include <math.h>

#define N 6144
#define FEA 32
#define NBW 4
#define NITER 4

// ---------------- K0: pack X (f32[N][3]) -> xp (f64[N][4] = x,y,z,|x|^2) ---
__global__ __launch_bounds__(256) void k_init(const float* __restrict__ X,
                                              double* __restrict__ xp) {
    int i = blockIdx.x * 256 + threadIdx.x;
    if (i >= N) return;
    double x = (double)X[3 * i + 0];
    double y = (double)X[3 * i + 1];
    double z = (double)X[3 * i + 2];
    double* p = xp + (size_t)i * 4;
    p[0] = x; p[1] = y; p[2] = z;
    p[3] = fma(x, x, fma(y, y, z * z));   // same formula as inner loop -> diag u > q always
}

// ---------------- K1: per-iteration BN batch stats (sum, sumsq per feature) --
__global__ __launch_bounds__(256) void k_mlp_stats(const float* __restrict__ Xfea,
                                                   const float* __restrict__ W1,
                                                   const float* __restrict__ b1,
                                                   float* __restrict__ partials) {
    __shared__ float w1s[FEA * FEA];
    __shared__ float hl[256][FEA + 1];
    __shared__ float r2[8][FEA][2];
    const int iter = blockIdx.y, chunk = blockIdx.x;

    const float* W1i = W1 + iter * FEA * FEA;
    for (int t = threadIdx.x; t < FEA * FEA; t += 256) w1s[t] = W1i[t];
    __syncthreads();

    const int row = chunk * 256 + threadIdx.x;
    float fea[FEA];
    const float4* fr = (const float4*)(Xfea + (size_t)row * FEA);
#pragma unroll
    for (int q = 0; q < FEA / 4; q++) {
        float4 v = fr[q];
        fea[4 * q + 0] = v.x; fea[4 * q + 1] = v.y;
        fea[4 * q + 2] = v.z; fea[4 * q + 3] = v.w;
    }
    float h[FEA];
#pragma unroll
    for (int f = 0; f < FEA; f++) h[f] = b1[iter * FEA + f];
    const float4* w1v = (const float4*)w1s;
#pragma unroll
    for (int k = 0; k < FEA; k++) {
        float a = fea[k];
#pragma unroll
        for (int f4 = 0; f4 < FEA / 4; f4++) {
            float4 wv = w1v[k * (FEA / 4) + f4];
            h[4 * f4 + 0] = fmaf(a, wv.x, h[4 * f4 + 0]);
            h[4 * f4 + 1] = fmaf(a, wv.y, h[4 * f4 + 1]);
            h[4 * f4 + 2] = fmaf(a, wv.z, h[4 * f4 + 2]);
            h[4 * f4 + 3] = fmaf(a, wv.w, h[4 * f4 + 3]);
        }
    }
#pragma unroll
    for (int f = 0; f < FEA; f++) hl[threadIdx.x][f] = h[f];
    __syncthreads();
    {
        int f = threadIdx.x & 31, g = threadIdx.x >> 5;
        float s = 0.f, q = 0.f;
#pragma unroll
        for (int r = 0; r < 32; r++) {
            float v = hl[g * 32 + r][f];
            s += v;
            q = fmaf(v, v, q);
        }
        r2[g][f][0] = s; r2[g][f][1] = q;
    }
    __syncthreads();
    if (threadIdx.x < FEA) {
        int f = threadIdx.x;
        float s = 0.f, q = 0.f;
#pragma unroll
        for (int g = 0; g < 8; g++) { s += r2[g][f][0]; q += r2[g][f][1]; }
        size_t o = ((size_t)(iter * 24 + chunk) * FEA + f) * 2;
        partials[o + 0] = s;
        partials[o + 1] = q;
    }
}

// ---------------- K2: fold BN into per-feature scale/shift --------------------
__global__ void k_bn(const float* __restrict__ partials,
                     const float* __restrict__ gamma,
                     const float* __restrict__ beta,
                     float* __restrict__ ss) {
    int iter = blockIdx.x;
    int f = threadIdx.x;   // 32 threads
    float s = 0.f, q = 0.f;
    for (int c = 0; c < 24; c++) {
        size_t o = ((size_t)(iter * 24 + c) * FEA + f) * 2;
        s += partials[o + 0];
        q += partials[o + 1];
    }
    float mu  = s / (float)N;
    float var = q / (float)N - mu * mu;          // biased var
    float rstd = 1.0f / sqrtf(var + 1e-5f);
    float sc = gamma[iter * FEA + f] * rstd;
    float sh = beta[iter * FEA + f] - mu * sc;
    ss[(iter * FEA + f) * 2 + 0] = sc;
    ss[(iter * FEA + f) * 2 + 1] = sh;
}

// ---------------- K3: recompute h, BN+ReLU, W2, softmax -> w[iter][N][4] -----
__global__ __launch_bounds__(256) void k_wts(const float* __restrict__ Xfea,
                                             const float* __restrict__ W1,
                                             const float* __restrict__ b1,
                                             const float* __restrict__ ss,
                                             const float* __restrict__ W2,
                                             const float* __restrict__ b2,
                                             float* __restrict__ wall) {
    __shared__ float w1s[FEA * FEA];
    __shared__ float w2s[FEA * NBW];
    __shared__ float scs[FEA], shs[FEA];
    const int iter = blockIdx.y, chunk = blockIdx.x;

    const float* W1i = W1 + iter * FEA * FEA;
    for (int t = threadIdx.x; t < FEA * FEA; t += 256) w1s[t] = W1i[t];
    if (threadIdx.x < FEA * NBW) w2s[threadIdx.x] = W2[iter * FEA * NBW + threadIdx.x];
    if (threadIdx.x < FEA) {
        scs[threadIdx.x] = ss[(iter * FEA + threadIdx.x) * 2 + 0];
        shs[threadIdx.x] = ss[(iter * FEA + threadIdx.x) * 2 + 1];
    }
    __syncthreads();

    const int row = chunk * 256 + threadIdx.x;
    float fea[FEA];
    const float4* fr = (const float4*)(Xfea + (size_t)row * FEA);
#pragma unroll
    for (int q = 0; q < FEA / 4; q++) {
        float4 v = fr[q];
        fea[4 * q + 0] = v.x; fea[4 * q + 1] = v.y;
        fea[4 * q + 2] = v.z; fea[4 * q + 3] = v.w;
    }
    float h[FEA];
#pragma unroll
    for (int f = 0; f < FEA; f++) h[f] = b1[iter * FEA + f];
    const float4* w1v = (const float4*)w1s;
#pragma unroll
    for (int k = 0; k < FEA; k++) {
        float a = fea[k];
#pragma unroll
        for (int f4 = 0; f4 < FEA / 4; f4++) {
            float4 wv = w1v[k * (FEA / 4) + f4];
            h[4 * f4 + 0] = fmaf(a, wv.x, h[4 * f4 + 0]);
            h[4 * f4 + 1] = fmaf(a, wv.y, h[4 * f4 + 1]);
            h[4 * f4 + 2] = fmaf(a, wv.z, h[4 * f4 + 2]);
            h[4 * f4 + 3] = fmaf(a, wv.w, h[4 * f4 + 3]);
        }
    }
    float l0 = b2[iter * NBW + 0], l1 = b2[iter * NBW + 1];
    float l2 = b2[iter * NBW + 2], l3 = b2[iter * NBW + 3];
#pragma unroll
    for (int f = 0; f < FEA; f++) {
        float hn = fmaxf(fmaf(h[f], scs[f], shs[f]), 0.0f);
        l0 = fmaf(hn, w2s[f * NBW + 0], l0);
        l1 = fmaf(hn, w2s[f * NBW + 1], l1);
        l2 = fmaf(hn, w2s[f * NBW + 2], l2);
        l3 = fmaf(hn, w2s[f * NBW + 3], l3);
    }
    float m = fmaxf(fmaxf(l0, l1), fmaxf(l2, l3));
    float e0 = expf(l0 - m), e1 = expf(l1 - m), e2 = expf(l2 - m), e3 = expf(l3 - m);
    float inv = 1.0f / (((e0 + e1) + e2) + e3);
    float4 w4;
    w4.x = e0 * inv; w4.y = e1 * inv; w4.z = e2 * inv; w4.w = e3 * inv;
    *(float4*)(wall + ((size_t)iter * N + row) * 4) = w4;
}

// ---------------- K4a: meanshift partial (split-K over j) ---------------------
// grid = 1536 blocks (row-group = bid>>1, j-half = bid&1), 4 waves, 2 rows/wave.
// v8: LDS tile sharing. All 4 waves consume the same 64-point j-tile; stage it
// once per block (256 threads x 8B coalesced load -> 8 lines/wave instead of 64)
// into a double-buffered LDS tile padded to 40B/point (4-way bank conflicts max).
// Issue-early/write-late: global load issued at loop top, ds_write after compute.
__global__ __launch_bounds__(256) void k_ms_part(const double* __restrict__ xin,
                                                 float4* __restrict__ part) {
    __shared__ double tile[2][64 * 5];   // [buf][point*5 + comp], 40B/point

    const int wv = threadIdx.x >> 6;
    const int ln = threadIdx.x & 63;
    const int g  = blockIdx.x >> 1;
    const int jh = blockIdx.x & 1;
    const int r0 = g * 8 + wv * 2;
    const int jbeg = jh * (N / 2);
    const int NSTEP = (N / 2) / 64;      // 48

    const int sp = threadIdx.x >> 2;     // staging: point 0..63
    const int sc = threadIdx.x & 3;      // staging: component 0..3

    double xi[2][3], q[2][4];
#pragma unroll
    for (int r = 0; r < 2; r++) {
        const double* p = xin + (size_t)(r0 + r) * 4;
        xi[r][0] = p[0]; xi[r][1] = p[1]; xi[r][2] = p[2];
        double sqi = p[3];
        q[r][0] = (sqi - 0.25) * 0.5;
        q[r][1] = (sqi - 1.0)  * 0.5;
        q[r][2] = (sqi - 4.0)  * 0.5;
        q[r][3] = (sqi - 16.0) * 0.5;
    }

    float ac[2][4][3];
    int cn[2][4];
#pragma unroll
    for (int r = 0; r < 2; r++)
#pragma unroll
        for (int b = 0; b < 4; b++) {
            cn[r][b] = 0;
            ac[r][b][0] = 0.f; ac[r][b][1] = 0.f; ac[r][b][2] = 0.f;
        }

    // stage tile 0
    tile[0][sp * 5 + sc] = xin[(size_t)(jbeg + sp) * 4 + sc];
    __syncthreads();

    int cur = 0;
    for (int s = 0; s < NSTEP; s++) {
        // issue next tile's global load early (T14: consumed after compute)
        double stg = 0.0;
        const bool do_stage = (s + 1 < NSTEP);
        if (do_stage)
            stg = xin[(size_t)(jbeg + (s + 1) * 64 + sp) * 4 + sc];

        // compute from tile[cur]
        double xj0 = tile[cur][ln * 5 + 0];
        double xj1 = tile[cur][ln * 5 + 1];
        double xj2 = tile[cur][ln * 5 + 2];
        double sqj = tile[cur][ln * 5 + 3];
        float fx = (float)xj0, fy = (float)xj1, fz = (float)xj2;

#pragma unroll
        for (int r = 0; r < 2; r++) {
            double t = fma(xi[r][0], xj0, fma(xi[r][1], xj1, xi[r][2] * xj2));
            double u = fma(-0.5, sqj, t);   // d2 <= c  <=>  u >= q[r][b]
            bool m0 = u >= q[r][0];
            bool m1 = u >= q[r][1];
            bool m2 = u >= q[r][2];
            bool m3 = u >= q[r][3];
            cn[r][0] += (int)__popcll(__ballot(m0));
            cn[r][1] += (int)__popcll(__ballot(m1));
            cn[r][2] += (int)__popcll(__ballot(m2));
            cn[r][3] += (int)__popcll(__ballot(m3));
            float c0 = m0 ? 1.0f : 0.0f;
            float c1 = m1 ? 1.0f : 0.0f;
            float c2 = m2 ? 1.0f : 0.0f;
            float c3 = m3 ? 1.0f : 0.0f;
            ac[r][0][0] = fmaf(c0, fx, ac[r][0][0]);
            ac[r][0][1] = fmaf(c0, fy, ac[r][0][1]);
            ac[r][0][2] = fmaf(c0, fz, ac[r][0][2]);
            ac[r][1][0] = fmaf(c1, fx, ac[r][1][0]);
            ac[r][1][1] = fmaf(c1, fy, ac[r][1][1]);
            ac[r][1][2] = fmaf(c1, fz, ac[r][1][2]);
            ac[r][2][0] = fmaf(c2, fx, ac[r][2][0]);
            ac[r][2][1] = fmaf(c2, fy, ac[r][2][1]);
            ac[r][2][2] = fmaf(c2, fz, ac[r][2][2]);
            ac[r][3][0] = fmaf(c3, fx, ac[r][3][0]);
            ac[r][3][1] = fmaf(c3, fy, ac[r][3][1]);
            ac[r][3][2] = fmaf(c3, fz, ac[r][3][2]);
        }

        // write staged value into the other buffer, then sync
        if (do_stage)
            tile[cur ^ 1][sp * 5 + sc] = stg;
        __syncthreads();
        cur ^= 1;
    }

    // deterministic fixed-tree wave reduction
#pragma unroll
    for (int r = 0; r < 2; r++)
#pragma unroll
        for (int b = 0; b < 4; b++)
#pragma unroll
            for (int k = 0; k < 3; k++) {
                float v = ac[r][b][k];
#pragma unroll
                for (int off = 32; off; off >>= 1) v += __shfl_xor(v, off, 64);
                ac[r][b][k] = v;
            }

    if (ln == 0) {
#pragma unroll
        for (int r = 0; r < 2; r++) {
            const int row = r0 + r;
#pragma unroll
            for (int b = 0; b < 4; b++) {
                float4 v;
                v.x = ac[r][b][0]; v.y = ac[r][b][1]; v.z = ac[r][b][2];
                v.w = (float)cn[r][b];
                part[((size_t)row * 2 + jh) * 4 + b] = v;
            }
        }
    }
}

// ---------------- K4b: combine partials + epilogue ----------------------------
__global__ __launch_bounds__(256) void k_comb(const float4* __restrict__ part,
                                              const float* __restrict__ wt,
                                              double* __restrict__ xout,
                                              float* __restrict__ fout) {
    const int row = blockIdx.x * 256 + threadIdx.x;
    if (row >= N) return;

    double sx[4], sy[4], sz[4], c[4];
#pragma unroll
    for (int b = 0; b < 4; b++) {
        float4 p0 = part[((size_t)row * 2 + 0) * 4 + b];
        float4 p1 = part[((size_t)row * 2 + 1) * 4 + b];
        sx[b] = (double)(p0.x + p1.x);
        sy[b] = (double)(p0.y + p1.y);
        sz[b] = (double)(p0.z + p1.z);
        c[b]  = (double)(p0.w + p1.w);   // integer-valued, exact
    }

    const float* wr = wt + (size_t)row * 4;
    double w0 = (double)wr[0], w1 = (double)wr[1];
    double w2 = (double)wr[2], w3 = (double)wr[3];
    double wsum = ((w0 + w1) + w2) + w3;

    double o[3];
    {
        double s = w0 * (sx[0] / c[0]);
        s = fma(w1, sx[1] / c[1], s);
        s = fma(w2, sx[2] / c[2], s);
        s = fma(w3, sx[3] / c[3], s);
        o[0] = s / wsum;
    }
    {
        double s = w0 * (sy[0] / c[0]);
        s = fma(w1, sy[1] / c[1], s);
        s = fma(w2, sy[2] / c[2], s);
        s = fma(w3, sy[3] / c[3], s);
        o[1] = s / wsum;
    }
    {
        double s = w0 * (sz[0] / c[0]);
        s = fma(w1, sz[1] / c[1], s);
        s = fma(w2, sz[2] / c[2], s);
        s = fma(w3, sz[3] / c[3], s);
        o[2] = s / wsum;
    }

    double* po = xout + (size_t)row * 4;
    po[0] = o[0]; po[1] = o[1]; po[2] = o[2];
    po[3] = fma(o[0], o[0], fma(o[1], o[1], o[2] * o[2]));
    float* pf = fout + (size_t)row * 3;
    pf[0] = (float)o[0]; pf[1] = (float)o[1]; pf[2] = (float)o[2];
}

extern "C" void kernel_launch(void* const* d_in, const int* in_sizes, int n_in,
                              void* d_out, int out_size, void* d_ws, size_t ws_size,
                              hipStream_t stream) {
    const float* X     = (const float*)d_in[0];
    const float* Xfea  = (const float*)d_in[1];
    const float* W1    = (const float*)d_in[2];
    const float* b1    = (const float*)d_in[3];
    const float* gamma = (const float*)d_in[4];
    const float* beta  = (const float*)d_in[5];
    const float* W2    = (const float*)d_in[6];
    const float* b2    = (const float*)d_in[7];
    float* out = (float*)d_out;

    // ws layout
    char* ws = (char*)d_ws;
    double* xp    = (double*)ws;                       // [2][N][4] f64  = 393216 B
    float*  wall  = (float*)(ws + 393216);             // [4][N][4] f32  = 393216 B
    float*  parts = (float*)(ws + 786432);             // [4][24][32][2] = 24576 B
    float*  ssbuf = (float*)(ws + 811008);             // [4][32][2]     = 1024 B
    float4* part2 = (float4*)(ws + 812032);            // [N][2][4] f4   = 786432 B

    k_init<<<24, 256, 0, stream>>>(X, xp);
    k_mlp_stats<<<dim3(24, NITER), 256, 0, stream>>>(Xfea, W1, b1, parts);
    k_bn<<<NITER, 32, 0, stream>>>(parts, gamma, beta, ssbuf);
    k_wts<<<dim3(24, NITER), 256, 0, stream>>>(Xfea, W1, b1, ssbuf, W2, b2, wall);

    for (int it = 0; it < NITER; it++) {
        const double* xin  = xp + (size_t)(it & 1) * N * 4;
        double*       xout = xp + (size_t)((it + 1) & 1) * N * 4;
        k_ms_part<<<1536, 256, 0, stream>>>(xin, part2);
        k_comb<<<24, 256, 0, stream>>>(part2, wall + (size_t)it * N * 4, xout, out);
    }
}

// Round 12
// 161.550 us; speedup vs baseline: 1.1596x; 1.1596x over previous
//
#include <hip/hip_runtime.h>
#include <math.h>

#define N 6144
#define FEA 32
#define NBW 4
#define NITER 4
#define NSPLIT 3
#define JLEN (N / NSPLIT)                 // 2048 = 32 steps of 64

// ---------------- K0: pack X (f32[N][3]) -> xp (f64[N][4] = x,y,z,|x|^2) ---
__global__ __launch_bounds__(256) void k_init(const float* __restrict__ X,
                                              double* __restrict__ xp) {
    int i = blockIdx.x * 256 + threadIdx.x;
    if (i >= N) return;
    double x = (double)X[3 * i + 0];
    double y = (double)X[3 * i + 1];
    double z = (double)X[3 * i + 2];
    double* p = xp + (size_t)i * 4;
    p[0] = x; p[1] = y; p[2] = z;
    p[3] = fma(x, x, fma(y, y, z * z));   // same formula as inner loop -> diag u > q always
}

// ---------------- K1: per-iteration BN batch stats (sum, sumsq per feature) --
__global__ __launch_bounds__(256) void k_mlp_stats(const float* __restrict__ Xfea,
                                                   const float* __restrict__ W1,
                                                   const float* __restrict__ b1,
                                                   float* __restrict__ partials) {
    __shared__ float w1s[FEA * FEA];
    __shared__ float hl[256][FEA + 1];
    __shared__ float r2[8][FEA][2];
    const int iter = blockIdx.y, chunk = blockIdx.x;

    const float* W1i = W1 + iter * FEA * FEA;
    for (int t = threadIdx.x; t < FEA * FEA; t += 256) w1s[t] = W1i[t];
    __syncthreads();

    const int row = chunk * 256 + threadIdx.x;
    float fea[FEA];
    const float4* fr = (const float4*)(Xfea + (size_t)row * FEA);
#pragma unroll
    for (int q = 0; q < FEA / 4; q++) {
        float4 v = fr[q];
        fea[4 * q + 0] = v.x; fea[4 * q + 1] = v.y;
        fea[4 * q + 2] = v.z; fea[4 * q + 3] = v.w;
    }
    float h[FEA];
#pragma unroll
    for (int f = 0; f < FEA; f++) h[f] = b1[iter * FEA + f];
    const float4* w1v = (const float4*)w1s;
#pragma unroll
    for (int k = 0; k < FEA; k++) {
        float a = fea[k];
#pragma unroll
        for (int f4 = 0; f4 < FEA / 4; f4++) {
            float4 wv = w1v[k * (FEA / 4) + f4];
            h[4 * f4 + 0] = fmaf(a, wv.x, h[4 * f4 + 0]);
            h[4 * f4 + 1] = fmaf(a, wv.y, h[4 * f4 + 1]);
            h[4 * f4 + 2] = fmaf(a, wv.z, h[4 * f4 + 2]);
            h[4 * f4 + 3] = fmaf(a, wv.w, h[4 * f4 + 3]);
        }
    }
#pragma unroll
    for (int f = 0; f < FEA; f++) hl[threadIdx.x][f] = h[f];
    __syncthreads();
    {
        int f = threadIdx.x & 31, g = threadIdx.x >> 5;
        float s = 0.f, q = 0.f;
#pragma unroll
        for (int r = 0; r < 32; r++) {
            float v = hl[g * 32 + r][f];
            s += v;
            q = fmaf(v, v, q);
        }
        r2[g][f][0] = s; r2[g][f][1] = q;
    }
    __syncthreads();
    if (threadIdx.x < FEA) {
        int f = threadIdx.x;
        float s = 0.f, q = 0.f;
#pragma unroll
        for (int g = 0; g < 8; g++) { s += r2[g][f][0]; q += r2[g][f][1]; }
        size_t o = ((size_t)(iter * 24 + chunk) * FEA + f) * 2;
        partials[o + 0] = s;
        partials[o + 1] = q;
    }
}

// ---------------- K2: fold BN into per-feature scale/shift --------------------
__global__ void k_bn(const float* __restrict__ partials,
                     const float* __restrict__ gamma,
                     const float* __restrict__ beta,
                     float* __restrict__ ss) {
    int iter = blockIdx.x;
    int f = threadIdx.x;   // 32 threads
    float s = 0.f, q = 0.f;
    for (int c = 0; c < 24; c++) {
        size_t o = ((size_t)(iter * 24 + c) * FEA + f) * 2;
        s += partials[o + 0];
        q += partials[o + 1];
    }
    float mu  = s / (float)N;
    float var = q / (float)N - mu * mu;          // biased var
    float rstd = 1.0f / sqrtf(var + 1e-5f);
    float sc = gamma[iter * FEA + f] * rstd;
    float sh = beta[iter * FEA + f] - mu * sc;
    ss[(iter * FEA + f) * 2 + 0] = sc;
    ss[(iter * FEA + f) * 2 + 1] = sh;
}

// ---------------- K3: recompute h, BN+ReLU, W2, softmax -> w[iter][N][4] -----
__global__ __launch_bounds__(256) void k_wts(const float* __restrict__ Xfea,
                                             const float* __restrict__ W1,
                                             const float* __restrict__ b1,
                                             const float* __restrict__ ss,
                                             const float* __restrict__ W2,
                                             const float* __restrict__ b2,
                                             float* __restrict__ wall) {
    __shared__ float w1s[FEA * FEA];
    __shared__ float w2s[FEA * NBW];
    __shared__ float scs[FEA], shs[FEA];
    const int iter = blockIdx.y, chunk = blockIdx.x;

    const float* W1i = W1 + iter * FEA * FEA;
    for (int t = threadIdx.x; t < FEA * FEA; t += 256) w1s[t] = W1i[t];
    if (threadIdx.x < FEA * NBW) w2s[threadIdx.x] = W2[iter * FEA * NBW + threadIdx.x];
    if (threadIdx.x < FEA) {
        scs[threadIdx.x] = ss[(iter * FEA + threadIdx.x) * 2 + 0];
        shs[threadIdx.x] = ss[(iter * FEA + threadIdx.x) * 2 + 1];
    }
    __syncthreads();

    const int row = chunk * 256 + threadIdx.x;
    float fea[FEA];
    const float4* fr = (const float4*)(Xfea + (size_t)row * FEA);
#pragma unroll
    for (int q = 0; q < FEA / 4; q++) {
        float4 v = fr[q];
        fea[4 * q + 0] = v.x; fea[4 * q + 1] = v.y;
        fea[4 * q + 2] = v.z; fea[4 * q + 3] = v.w;
    }
    float h[FEA];
#pragma unroll
    for (int f = 0; f < FEA; f++) h[f] = b1[iter * FEA + f];
    const float4* w1v = (const float4*)w1s;
#pragma unroll
    for (int k = 0; k < FEA; k++) {
        float a = fea[k];
#pragma unroll
        for (int f4 = 0; f4 < FEA / 4; f4++) {
            float4 wv = w1v[k * (FEA / 4) + f4];
            h[4 * f4 + 0] = fmaf(a, wv.x, h[4 * f4 + 0]);
            h[4 * f4 + 1] = fmaf(a, wv.y, h[4 * f4 + 1]);
            h[4 * f4 + 2] = fmaf(a, wv.z, h[4 * f4 + 2]);
            h[4 * f4 + 3] = fmaf(a, wv.w, h[4 * f4 + 3]);
        }
    }
    float l0 = b2[iter * NBW + 0], l1 = b2[iter * NBW + 1];
    float l2 = b2[iter * NBW + 2], l3 = b2[iter * NBW + 3];
#pragma unroll
    for (int f = 0; f < FEA; f++) {
        float hn = fmaxf(fmaf(h[f], scs[f], shs[f]), 0.0f);
        l0 = fmaf(hn, w2s[f * NBW + 0], l0);
        l1 = fmaf(hn, w2s[f * NBW + 1], l1);
        l2 = fmaf(hn, w2s[f * NBW + 2], l2);
        l3 = fmaf(hn, w2s[f * NBW + 3], l3);
    }
    float m = fmaxf(fmaxf(l0, l1), fmaxf(l2, l3));
    float e0 = expf(l0 - m), e1 = expf(l1 - m), e2 = expf(l2 - m), e3 = expf(l3 - m);
    float inv = 1.0f / (((e0 + e1) + e2) + e3);
    float4 w4;
    w4.x = e0 * inv; w4.y = e1 * inv; w4.z = e2 * inv; w4.w = e3 * inv;
    *(float4*)(wall + ((size_t)iter * N + row) * 4) = w4;
}

// ---------------- K4a: meanshift partial (3-way split-K over j) ---------------
// grid = 2304 blocks (row-group g = bid/3, j-third jh = bid%3), 4 waves,
// 2 rows/wave -> 9216 waves; 8192 resident = 8 waves/SIMD (VGPR 36 <= 64).
// f64 decisions (transformed cmp), f32 accumulate, 1-deep prefetch (r7 WIN).
__global__ __launch_bounds__(256) void k_ms_part(const double* __restrict__ xin,
                                                 float4* __restrict__ part) {
    const int wv = threadIdx.x >> 6;
    const int ln = threadIdx.x & 63;
    const int g  = blockIdx.x / NSPLIT;
    const int jh = blockIdx.x % NSPLIT;
    const int r0 = g * 8 + wv * 2;
    const int jbeg = jh * JLEN;
    const int jend = jbeg + JLEN;

    double xi[2][3], q[2][4];
#pragma unroll
    for (int r = 0; r < 2; r++) {
        const double* p = xin + (size_t)(r0 + r) * 4;
        xi[r][0] = p[0]; xi[r][1] = p[1]; xi[r][2] = p[2];
        double sqi = p[3];
        q[r][0] = (sqi - 0.25) * 0.5;
        q[r][1] = (sqi - 1.0)  * 0.5;
        q[r][2] = (sqi - 4.0)  * 0.5;
        q[r][3] = (sqi - 16.0) * 0.5;
    }

    float ac[2][4][3];
    int cn[2][4];
#pragma unroll
    for (int r = 0; r < 2; r++)
#pragma unroll
        for (int b = 0; b < 4; b++) {
            cn[r][b] = 0;
            ac[r][b][0] = 0.f; ac[r][b][1] = 0.f; ac[r][b][2] = 0.f;
        }

    // preload first tile of this third
    const double* p0 = xin + (size_t)(jbeg + ln) * 4;
    double2 A = *(const double2*)p0;
    double2 B = *(const double2*)(p0 + 2);

    for (int j0 = jbeg; j0 < jend; j0 += 64) {
        int jn = (j0 + 64 < jend) ? (j0 + 64) : jbeg;  // wrap; values unused on last
        const double* pn = xin + (size_t)(jn + ln) * 4;
        double2 An = *(const double2*)pn;
        double2 Bn = *(const double2*)(pn + 2);

        float fx = (float)A.x, fy = (float)A.y, fz = (float)B.x;

#pragma unroll
        for (int r = 0; r < 2; r++) {
            double t = fma(xi[r][0], A.x, fma(xi[r][1], A.y, xi[r][2] * B.x));
            double u = fma(-0.5, B.y, t);   // d2 <= c  <=>  u >= q[r][b]
            bool m0 = u >= q[r][0];
            bool m1 = u >= q[r][1];
            bool m2 = u >= q[r][2];
            bool m3 = u >= q[r][3];
            cn[r][0] += (int)__popcll(__ballot(m0));
            cn[r][1] += (int)__popcll(__ballot(m1));
            cn[r][2] += (int)__popcll(__ballot(m2));
            cn[r][3] += (int)__popcll(__ballot(m3));
            float c0 = m0 ? 1.0f : 0.0f;
            float c1 = m1 ? 1.0f : 0.0f;
            float c2 = m2 ? 1.0f : 0.0f;
            float c3 = m3 ? 1.0f : 0.0f;
            ac[r][0][0] = fmaf(c0, fx, ac[r][0][0]);
            ac[r][0][1] = fmaf(c0, fy, ac[r][0][1]);
            ac[r][0][2] = fmaf(c0, fz, ac[r][0][2]);
            ac[r][1][0] = fmaf(c1, fx, ac[r][1][0]);
            ac[r][1][1] = fmaf(c1, fy, ac[r][1][1]);
            ac[r][1][2] = fmaf(c1, fz, ac[r][1][2]);
            ac[r][2][0] = fmaf(c2, fx, ac[r][2][0]);
            ac[r][2][1] = fmaf(c2, fy, ac[r][2][1]);
            ac[r][2][2] = fmaf(c2, fz, ac[r][2][2]);
            ac[r][3][0] = fmaf(c3, fx, ac[r][3][0]);
            ac[r][3][1] = fmaf(c3, fy, ac[r][3][1]);
            ac[r][3][2] = fmaf(c3, fz, ac[r][3][2]);
        }
        A = An; B = Bn;
    }

    // deterministic fixed-tree wave reduction
#pragma unroll
    for (int r = 0; r < 2; r++)
#pragma unroll
        for (int b = 0; b < 4; b++)
#pragma unroll
            for (int k = 0; k < 3; k++) {
                float v = ac[r][b][k];
#pragma unroll
                for (int off = 32; off; off >>= 1) v += __shfl_xor(v, off, 64);
                ac[r][b][k] = v;
            }

    if (ln == 0) {
#pragma unroll
        for (int r = 0; r < 2; r++) {
            const int row = r0 + r;
#pragma unroll
            for (int b = 0; b < 4; b++) {
                float4 v;
                v.x = ac[r][b][0]; v.y = ac[r][b][1]; v.z = ac[r][b][2];
                v.w = (float)cn[r][b];
                part[((size_t)row * NSPLIT + jh) * 4 + b] = v;
            }
        }
    }
}

// ---------------- K4b: combine partials + epilogue ----------------------------
__global__ __launch_bounds__(256) void k_comb(const float4* __restrict__ part,
                                              const float* __restrict__ wt,
                                              double* __restrict__ xout,
                                              float* __restrict__ fout) {
    const int row = blockIdx.x * 256 + threadIdx.x;
    if (row >= N) return;

    double sx[4], sy[4], sz[4], c[4];
#pragma unroll
    for (int b = 0; b < 4; b++) {
        sx[b] = 0.0; sy[b] = 0.0; sz[b] = 0.0; c[b] = 0.0;
    }
#pragma unroll
    for (int h = 0; h < NSPLIT; h++) {
#pragma unroll
        for (int b = 0; b < 4; b++) {
            float4 p = part[((size_t)row * NSPLIT + h) * 4 + b];
            sx[b] += (double)p.x;
            sy[b] += (double)p.y;
            sz[b] += (double)p.z;
            c[b]  += (double)p.w;   // integer-valued, exact
        }
    }

    const float* wr = wt + (size_t)row * 4;
    double w0 = (double)wr[0], w1 = (double)wr[1];
    double w2 = (double)wr[2], w3 = (double)wr[3];
    double wsum = ((w0 + w1) + w2) + w3;

    double o[3];
    {
        double s = w0 * (sx[0] / c[0]);
        s = fma(w1, sx[1] / c[1], s);
        s = fma(w2, sx[2] / c[2], s);
        s = fma(w3, sx[3] / c[3], s);
        o[0] = s / wsum;
    }
    {
        double s = w0 * (sy[0] / c[0]);
        s = fma(w1, sy[1] / c[1], s);
        s = fma(w2, sy[2] / c[2], s);
        s = fma(w3, sy[3] / c[3], s);
        o[1] = s / wsum;
    }
    {
        double s = w0 * (sz[0] / c[0]);
        s = fma(w1, sz[1] / c[1], s);
        s = fma(w2, sz[2] / c[2], s);
        s = fma(w3, sz[3] / c[3], s);
        o[2] = s / wsum;
    }

    double* po = xout + (size_t)row * 4;
    po[0] = o[0]; po[1] = o[1]; po[2] = o[2];
    po[3] = fma(o[0], o[0], fma(o[1], o[1], o[2] * o[2]));
    float* pf = fout + (size_t)row * 3;
    pf[0] = (float)o[0]; pf[1] = (float)o[1]; pf[2] = (float)o[2];
}

extern "C" void kernel_launch(void* const* d_in, const int* in_sizes, int n_in,
                              void* d_out, int out_size, void* d_ws, size_t ws_size,
                              hipStream_t stream) {
    const float* X     = (const float*)d_in[0];
    const float* Xfea  = (const float*)d_in[1];
    const float* W1    = (const float*)d_in[2];
    const float* b1    = (const float*)d_in[3];
    const float* gamma = (const float*)d_in[4];
    const float* beta  = (const float*)d_in[5];
    const float* W2    = (const float*)d_in[6];
    const float* b2    = (const float*)d_in[7];
    float* out = (float*)d_out;

    // ws layout
    char* ws = (char*)d_ws;
    double* xp    = (double*)ws;                       // [2][N][4] f64  = 393216 B
    float*  wall  = (float*)(ws + 393216);             // [4][N][4] f32  = 393216 B
    float*  parts = (float*)(ws + 786432);             // [4][24][32][2] = 24576 B
    float*  ssbuf = (float*)(ws + 811008);             // [4][32][2]     = 1024 B
    float4* part2 = (float4*)(ws + 812032);            // [N][3][4] f4   = 1179648 B

    k_init<<<24, 256, 0, stream>>>(X, xp);
    k_mlp_stats<<<dim3(24, NITER), 256, 0, stream>>>(Xfea, W1, b1, parts);
    k_bn<<<NITER, 32, 0, stream>>>(parts, gamma, beta, ssbuf);
    k_wts<<<dim3(24, NITER), 256, 0, stream>>>(Xfea, W1, b1, ssbuf, W2, b2, wall);

    for (int it = 0; it < NITER; it++) {
        const double* xin  = xp + (size_t)(it & 1) * N * 4;
        double*       xout = xp + (size_t)((it + 1) & 1) * N * 4;
        k_ms_part<<<768 * NSPLIT, 256, 0, stream>>>(xin, part2);
        k_comb<<<24, 256, 0, stream>>>(part2, wall + (size_t)it * N * 4, xout, out);
    }
}

// Round 13
// 155.307 us; speedup vs baseline: 1.2062x; 1.0402x over previous
//
#include <hip/hip_runtime.h>
#include <math.h>

#define N 6144
#define FEA 32
#define NBW 4
#define NITER 4
#define NSPLIT 3
#define JLEN (N / NSPLIT)                 // 2048 = 32 steps of 64
#define NSTEPS (JLEN / 64)                // 32

// ---------------- K0: pack X (f32[N][3]) -> xp (f64[N][4] = x,y,z,-0.5|x|^2) -
__global__ __launch_bounds__(256) void k_init(const float* __restrict__ X,
                                              double* __restrict__ xp) {
    int i = blockIdx.x * 256 + threadIdx.x;
    if (i >= N) return;
    double x = (double)X[3 * i + 0];
    double y = (double)X[3 * i + 1];
    double z = (double)X[3 * i + 2];
    double* p = xp + (size_t)i * 4;
    p[0] = x; p[1] = y; p[2] = z;
    double sq = fma(x, x, fma(y, y, z * z));
    p[3] = -0.5 * sq;                     // exact scaling; sq recoverable exactly
}

// ---------------- K1: per-iteration BN batch stats (sum, sumsq per feature) --
__global__ __launch_bounds__(256) void k_mlp_stats(const float* __restrict__ Xfea,
                                                   const float* __restrict__ W1,
                                                   const float* __restrict__ b1,
                                                   float* __restrict__ partials) {
    __shared__ float w1s[FEA * FEA];
    __shared__ float hl[256][FEA + 1];
    __shared__ float r2[8][FEA][2];
    const int iter = blockIdx.y, chunk = blockIdx.x;

    const float* W1i = W1 + iter * FEA * FEA;
    for (int t = threadIdx.x; t < FEA * FEA; t += 256) w1s[t] = W1i[t];
    __syncthreads();

    const int row = chunk * 256 + threadIdx.x;
    float fea[FEA];
    const float4* fr = (const float4*)(Xfea + (size_t)row * FEA);
#pragma unroll
    for (int q = 0; q < FEA / 4; q++) {
        float4 v = fr[q];
        fea[4 * q + 0] = v.x; fea[4 * q + 1] = v.y;
        fea[4 * q + 2] = v.z; fea[4 * q + 3] = v.w;
    }
    float h[FEA];
#pragma unroll
    for (int f = 0; f < FEA; f++) h[f] = b1[iter * FEA + f];
    const float4* w1v = (const float4*)w1s;
#pragma unroll
    for (int k = 0; k < FEA; k++) {
        float a = fea[k];
#pragma unroll
        for (int f4 = 0; f4 < FEA / 4; f4++) {
            float4 wv = w1v[k * (FEA / 4) + f4];
            h[4 * f4 + 0] = fmaf(a, wv.x, h[4 * f4 + 0]);
            h[4 * f4 + 1] = fmaf(a, wv.y, h[4 * f4 + 1]);
            h[4 * f4 + 2] = fmaf(a, wv.z, h[4 * f4 + 2]);
            h[4 * f4 + 3] = fmaf(a, wv.w, h[4 * f4 + 3]);
        }
    }
#pragma unroll
    for (int f = 0; f < FEA; f++) hl[threadIdx.x][f] = h[f];
    __syncthreads();
    {
        int f = threadIdx.x & 31, g = threadIdx.x >> 5;
        float s = 0.f, q = 0.f;
#pragma unroll
        for (int r = 0; r < 32; r++) {
            float v = hl[g * 32 + r][f];
            s += v;
            q = fmaf(v, v, q);
        }
        r2[g][f][0] = s; r2[g][f][1] = q;
    }
    __syncthreads();
    if (threadIdx.x < FEA) {
        int f = threadIdx.x;
        float s = 0.f, q = 0.f;
#pragma unroll
        for (int g = 0; g < 8; g++) { s += r2[g][f][0]; q += r2[g][f][1]; }
        size_t o = ((size_t)(iter * 24 + chunk) * FEA + f) * 2;
        partials[o + 0] = s;
        partials[o + 1] = q;
    }
}

// ---------------- K2: fold BN into per-feature scale/shift --------------------
__global__ void k_bn(const float* __restrict__ partials,
                     const float* __restrict__ gamma,
                     const float* __restrict__ beta,
                     float* __restrict__ ss) {
    int iter = blockIdx.x;
    int f = threadIdx.x;   // 32 threads
    float s = 0.f, q = 0.f;
    for (int c = 0; c < 24; c++) {
        size_t o = ((size_t)(iter * 24 + c) * FEA + f) * 2;
        s += partials[o + 0];
        q += partials[o + 1];
    }
    float mu  = s / (float)N;
    float var = q / (float)N - mu * mu;          // biased var
    float rstd = 1.0f / sqrtf(var + 1e-5f);
    float sc = gamma[iter * FEA + f] * rstd;
    float sh = beta[iter * FEA + f] - mu * sc;
    ss[(iter * FEA + f) * 2 + 0] = sc;
    ss[(iter * FEA + f) * 2 + 1] = sh;
}

// ---------------- K3: recompute h, BN+ReLU, W2, softmax -> w[iter][N][4] -----
__global__ __launch_bounds__(256) void k_wts(const float* __restrict__ Xfea,
                                             const float* __restrict__ W1,
                                             const float* __restrict__ b1,
                                             const float* __restrict__ ss,
                                             const float* __restrict__ W2,
                                             const float* __restrict__ b2,
                                             float* __restrict__ wall) {
    __shared__ float w1s[FEA * FEA];
    __shared__ float w2s[FEA * NBW];
    __shared__ float scs[FEA], shs[FEA];
    const int iter = blockIdx.y, chunk = blockIdx.x;

    const float* W1i = W1 + iter * FEA * FEA;
    for (int t = threadIdx.x; t < FEA * FEA; t += 256) w1s[t] = W1i[t];
    if (threadIdx.x < FEA * NBW) w2s[threadIdx.x] = W2[iter * FEA * NBW + threadIdx.x];
    if (threadIdx.x < FEA) {
        scs[threadIdx.x] = ss[(iter * FEA + threadIdx.x) * 2 + 0];
        shs[threadIdx.x] = ss[(iter * FEA + threadIdx.x) * 2 + 1];
    }
    __syncthreads();

    const int row = chunk * 256 + threadIdx.x;
    float fea[FEA];
    const float4* fr = (const float4*)(Xfea + (size_t)row * FEA);
#pragma unroll
    for (int q = 0; q < FEA / 4; q++) {
        float4 v = fr[q];
        fea[4 * q + 0] = v.x; fea[4 * q + 1] = v.y;
        fea[4 * q + 2] = v.z; fea[4 * q + 3] = v.w;
    }
    float h[FEA];
#pragma unroll
    for (int f = 0; f < FEA; f++) h[f] = b1[iter * FEA + f];
    const float4* w1v = (const float4*)w1s;
#pragma unroll
    for (int k = 0; k < FEA; k++) {
        float a = fea[k];
#pragma unroll
        for (int f4 = 0; f4 < FEA / 4; f4++) {
            float4 wv = w1v[k * (FEA / 4) + f4];
            h[4 * f4 + 0] = fmaf(a, wv.x, h[4 * f4 + 0]);
            h[4 * f4 + 1] = fmaf(a, wv.y, h[4 * f4 + 1]);
            h[4 * f4 + 2] = fmaf(a, wv.z, h[4 * f4 + 2]);
            h[4 * f4 + 3] = fmaf(a, wv.w, h[4 * f4 + 3]);
        }
    }
    float l0 = b2[iter * NBW + 0], l1 = b2[iter * NBW + 1];
    float l2 = b2[iter * NBW + 2], l3 = b2[iter * NBW + 3];
#pragma unroll
    for (int f = 0; f < FEA; f++) {
        float hn = fmaxf(fmaf(h[f], scs[f], shs[f]), 0.0f);
        l0 = fmaf(hn, w2s[f * NBW + 0], l0);
        l1 = fmaf(hn, w2s[f * NBW + 1], l1);
        l2 = fmaf(hn, w2s[f * NBW + 2], l2);
        l3 = fmaf(hn, w2s[f * NBW + 3], l3);
    }
    float m = fmaxf(fmaxf(l0, l1), fmaxf(l2, l3));
    float e0 = expf(l0 - m), e1 = expf(l1 - m), e2 = expf(l2 - m), e3 = expf(l3 - m);
    float inv = 1.0f / (((e0 + e1) + e2) + e3);
    float4 w4;
    w4.x = e0 * inv; w4.y = e1 * inv; w4.z = e2 * inv; w4.w = e3 * inv;
    *(float4*)(wall + ((size_t)iter * N + row) * 4) = w4;
}

// ---------------- K4a: meanshift partial (3-way split-K over j) ---------------
// v9 = v8(r12) + inner-loop diet: 3-FMA u (tile.w = -0.5*sqj), 2x unrolled
// j-loop with static E/O register sets (no rotation movs), 1-deep prefetch.
// grid = 2304 blocks, 4 waves, 2 rows/wave -> 9216 waves, ~8 waves/SIMD.
__global__ __launch_bounds__(256) void k_ms_part(const double* __restrict__ xin,
                                                 float4* __restrict__ part) {
    const int wv = threadIdx.x >> 6;
    const int ln = threadIdx.x & 63;
    const int g  = blockIdx.x / NSPLIT;
    const int jh = blockIdx.x % NSPLIT;
    const int r0 = g * 8 + wv * 2;
    const int jbeg = jh * JLEN;

    double xi[2][3], q[2][4];
#pragma unroll
    for (int r = 0; r < 2; r++) {
        const double* p = xin + (size_t)(r0 + r) * 4;
        xi[r][0] = p[0]; xi[r][1] = p[1]; xi[r][2] = p[2];
        double sqi = -2.0 * p[3];          // exact recovery
        q[r][0] = (sqi - 0.25) * 0.5;
        q[r][1] = (sqi - 1.0)  * 0.5;
        q[r][2] = (sqi - 4.0)  * 0.5;
        q[r][3] = (sqi - 16.0) * 0.5;
    }

    float ac[2][4][3];
    int cn[2][4];
#pragma unroll
    for (int r = 0; r < 2; r++)
#pragma unroll
        for (int b = 0; b < 4; b++) {
            cn[r][b] = 0;
            ac[r][b][0] = 0.f; ac[r][b][1] = 0.f; ac[r][b][2] = 0.f;
        }

    const double* pb = xin + (size_t)(jbeg + ln) * 4;   // lane base; tile s at +s*256

#define LOADT(LO, HI, SIDX) { const double* pp = pb + (size_t)(SIDX) * 256; \
                              LO = *(const double2*)pp; HI = *(const double2*)(pp + 2); }

#define COMPUTE(A_, B_) { \
    float fx = (float)A_.x, fy = (float)A_.y, fz = (float)B_.x; \
    _Pragma("unroll") \
    for (int r = 0; r < 2; r++) { \
        double u = fma(xi[r][0], A_.x, fma(xi[r][1], A_.y, fma(xi[r][2], B_.x, B_.y))); \
        bool m0 = u >= q[r][0]; \
        bool m1 = u >= q[r][1]; \
        bool m2 = u >= q[r][2]; \
        bool m3 = u >= q[r][3]; \
        cn[r][0] += (int)__popcll(__ballot(m0)); \
        cn[r][1] += (int)__popcll(__ballot(m1)); \
        cn[r][2] += (int)__popcll(__ballot(m2)); \
        cn[r][3] += (int)__popcll(__ballot(m3)); \
        float c0 = m0 ? 1.0f : 0.0f; \
        float c1 = m1 ? 1.0f : 0.0f; \
        float c2 = m2 ? 1.0f : 0.0f; \
        float c3 = m3 ? 1.0f : 0.0f; \
        ac[r][0][0] = fmaf(c0, fx, ac[r][0][0]); \
        ac[r][0][1] = fmaf(c0, fy, ac[r][0][1]); \
        ac[r][0][2] = fmaf(c0, fz, ac[r][0][2]); \
        ac[r][1][0] = fmaf(c1, fx, ac[r][1][0]); \
        ac[r][1][1] = fmaf(c1, fy, ac[r][1][1]); \
        ac[r][1][2] = fmaf(c1, fz, ac[r][1][2]); \
        ac[r][2][0] = fmaf(c2, fx, ac[r][2][0]); \
        ac[r][2][1] = fmaf(c2, fy, ac[r][2][1]); \
        ac[r][2][2] = fmaf(c2, fz, ac[r][2][2]); \
        ac[r][3][0] = fmaf(c3, fx, ac[r][3][0]); \
        ac[r][3][1] = fmaf(c3, fy, ac[r][3][1]); \
        ac[r][3][2] = fmaf(c3, fz, ac[r][3][2]); \
    } }

    double2 EA, EB, OA, OB;
    LOADT(EA, EB, 0)
    LOADT(OA, OB, 1)

    for (int it2 = 0; it2 < NSTEPS / 2; it2++) {
        const int se = (2 * it2 + 2 < NSTEPS) ? (2 * it2 + 2) : 0;  // wrap; unused on tail
        const int so = (2 * it2 + 3 < NSTEPS) ? (2 * it2 + 3) : 0;

        COMPUTE(EA, EB)          // step 2*it2
        LOADT(EA, EB, se)        // prefetch step 2*it2+2 (1-step lead)
        COMPUTE(OA, OB)          // step 2*it2+1
        LOADT(OA, OB, so)        // prefetch step 2*it2+3
    }

#undef LOADT
#undef COMPUTE

    // deterministic fixed-tree wave reduction
#pragma unroll
    for (int r = 0; r < 2; r++)
#pragma unroll
        for (int b = 0; b < 4; b++)
#pragma unroll
            for (int k = 0; k < 3; k++) {
                float v = ac[r][b][k];
#pragma unroll
                for (int off = 32; off; off >>= 1) v += __shfl_xor(v, off, 64);
                ac[r][b][k] = v;
            }

    if (ln == 0) {
#pragma unroll
        for (int r = 0; r < 2; r++) {
            const int row = r0 + r;
#pragma unroll
            for (int b = 0; b < 4; b++) {
                float4 v;
                v.x = ac[r][b][0]; v.y = ac[r][b][1]; v.z = ac[r][b][2];
                v.w = (float)cn[r][b];
                part[((size_t)row * NSPLIT + jh) * 4 + b] = v;
            }
        }
    }
}

// ---------------- K4b: combine partials + epilogue ----------------------------
__global__ __launch_bounds__(256) void k_comb(const float4* __restrict__ part,
                                              const float* __restrict__ wt,
                                              double* __restrict__ xout,
                                              float* __restrict__ fout) {
    const int row = blockIdx.x * 256 + threadIdx.x;
    if (row >= N) return;

    double sx[4], sy[4], sz[4], c[4];
#pragma unroll
    for (int b = 0; b < 4; b++) {
        sx[b] = 0.0; sy[b] = 0.0; sz[b] = 0.0; c[b] = 0.0;
    }
#pragma unroll
    for (int h = 0; h < NSPLIT; h++) {
#pragma unroll
        for (int b = 0; b < 4; b++) {
            float4 p = part[((size_t)row * NSPLIT + h) * 4 + b];
            sx[b] += (double)p.x;
            sy[b] += (double)p.y;
            sz[b] += (double)p.z;
            c[b]  += (double)p.w;   // integer-valued, exact
        }
    }

    const float* wr = wt + (size_t)row * 4;
    double w0 = (double)wr[0], w1 = (double)wr[1];
    double w2 = (double)wr[2], w3 = (double)wr[3];
    double wsum = ((w0 + w1) + w2) + w3;

    double o[3];
    {
        double s = w0 * (sx[0] / c[0]);
        s = fma(w1, sx[1] / c[1], s);
        s = fma(w2, sx[2] / c[2], s);
        s = fma(w3, sx[3] / c[3], s);
        o[0] = s / wsum;
    }
    {
        double s = w0 * (sy[0] / c[0]);
        s = fma(w1, sy[1] / c[1], s);
        s = fma(w2, sy[2] / c[2], s);
        s = fma(w3, sy[3] / c[3], s);
        o[1] = s / wsum;
    }
    {
        double s = w0 * (sz[0] / c[0]);
        s = fma(w1, sz[1] / c[1], s);
        s = fma(w2, sz[2] / c[2], s);
        s = fma(w3, sz[3] / c[3], s);
        o[2] = s / wsum;
    }

    double* po = xout + (size_t)row * 4;
    po[0] = o[0]; po[1] = o[1]; po[2] = o[2];
    double sq = fma(o[0], o[0], fma(o[1], o[1], o[2] * o[2]));
    po[3] = -0.5 * sq;
    float* pf = fout + (size_t)row * 3;
    pf[0] = (float)o[0]; pf[1] = (float)o[1]; pf[2] = (float)o[2];
}

extern "C" void kernel_launch(void* const* d_in, const int* in_sizes, int n_in,
                              void* d_out, int out_size, void* d_ws, size_t ws_size,
                              hipStream_t stream) {
    const float* X     = (const float*)d_in[0];
    const float* Xfea  = (const float*)d_in[1];
    const float* W1    = (const float*)d_in[2];
    const float* b1    = (const float*)d_in[3];
    const float* gamma = (const float*)d_in[4];
    const float* beta  = (const float*)d_in[5];
    const float* W2    = (const float*)d_in[6];
    const float* b2    = (const float*)d_in[7];
    float* out = (float*)d_out;

    // ws layout
    char* ws = (char*)d_ws;
    double* xp    = (double*)ws;                       // [2][N][4] f64  = 393216 B
    float*  wall  = (float*)(ws + 393216);             // [4][N][4] f32  = 393216 B
    float*  parts = (float*)(ws + 786432);             // [4][24][32][2] = 24576 B
    float*  ssbuf = (float*)(ws + 811008);             // [4][32][2]     = 1024 B
    float4* part2 = (float4*)(ws + 812032);            // [N][3][4] f4   = 1179648 B

    k_init<<<24, 256, 0, stream>>>(X, xp);
    k_mlp_stats<<<dim3(24, NITER), 256, 0, stream>>>(Xfea, W1, b1, parts);
    k_bn<<<NITER, 32, 0, stream>>>(parts, gamma, beta, ssbuf);
    k_wts<<<dim3(24, NITER), 256, 0, stream>>>(Xfea, W1, b1, ssbuf, W2, b2, wall);

    for (int it = 0; it < NITER; it++) {
        const double* xin  = xp + (size_t)(it & 1) * N * 4;
        double*       xout = xp + (size_t)((it + 1) & 1) * N * 4;
        k_ms_part<<<768 * NSPLIT, 256, 0, stream>>>(xin, part2);
        k_comb<<<24, 256, 0, stream>>>(part2, wall + (size_t)it * N * 4, xout, out);
    }
}